// Round 9
// baseline (1013.733 us; speedup 1.0000x reference)
//
#include <hip/hip_runtime.h>
#include <hip/hip_bf16.h>

#define N_USERS 100000
#define N_ITEMS 50000
#define N_TOT   150000
#define D       64
#define NBUCK   ((N_ITEMS + 255) >> 8)   // 196 coarse buckets of 256 items
#define BCAP    12288                    // bucket capacity (mean ~10.2K, +18 sigma)
#define CONVU_B 391                      // ceil(100000/256): user conv+ptr blocks
#define FLAG_B  48                       // ceil(3*4096/256)
#define SCAT_K  32                       // edges per thread in scatter section
#define PERM_B  ((N_TOT + 255) >> 8)     // 586 blocks for perm build

typedef float v2f __attribute__((ext_vector_type(2)));

// ---------------- helpers ----------------
__device__ __forceinline__ unsigned bf16rn(float f) {        // fp32 -> bf16 bits (RNE)
    unsigned x = __float_as_uint(f);
    return (x + 0x7FFFu + ((x >> 16) & 1u)) >> 16;
}
__device__ __forceinline__ unsigned packbf(float a, float b) {
    return bf16rn(a) | (bf16rn(b) << 16);
}
__device__ __forceinline__ int lower_bound(const int* __restrict__ a, int n, int key) {
    int lo = 0, hi = n;
    while (lo < hi) {
        int mid = (lo + hi) >> 1;
        if (a[mid] < key) lo = mid + 1; else hi = mid;
    }
    return lo;
}

// ---------------- preprocessing kernel A (R7-proven + degree hist) ----------------
__global__ __launch_bounds__(256) void preA_kernel(
        const float* __restrict__ embeds, const int* __restrict__ rows,
        const int* __restrict__ cols, int* __restrict__ user_ptr,
        unsigned* __restrict__ ebfS, float* __restrict__ invrow,
        const int* __restrict__ users, const int* __restrict__ pos,
        const int* __restrict__ neg, unsigned char* __restrict__ flags,
        int* __restrict__ ccur, int* __restrict__ tmp,
        unsigned short* __restrict__ cols16, int* __restrict__ gbins,
        int E, int B) {
    int b = blockIdx.x, t = threadIdx.x;
    if (b < CONVU_B) {
        __shared__ int ptr_s[257];
        __shared__ float inv_s[256];
        int base = b * 256;
        int r = base + t;
        int v = lower_bound(rows, E, r);
        ptr_s[t] = v;
        if (r <= N_USERS) user_ptr[r] = v;
        if (t == 0) ptr_s[256] = lower_bound(rows, E, base + 256);
        __syncthreads();
        if (r < N_USERS) {
            int deg = ptr_s[t + 1] - ptr_s[t];
            float inv = (deg > 0) ? (float)(1.0 / sqrt((double)deg)) : 0.f;
            inv_s[t] = inv;
            invrow[r] = inv;
            atomicAdd(&gbins[min(deg, 255)], 1);      // degree histogram (perm)
        } else inv_s[t] = 0.f;
        __syncthreads();
        int fl = t & 15;
        #pragma unroll
        for (int i = 0; i < 16; ++i) {
            int lr = i * 16 + (t >> 4);
            int row = base + lr;
            if (row < N_USERS) {
                float inv = inv_s[lr];
                float4 v4 = *(const float4*)(embeds + (size_t)row * D + fl * 4);
                uint2 o;
                o.x = packbf(inv * v4.x, inv * v4.y);
                o.y = packbf(inv * v4.z, inv * v4.w);
                *(uint2*)(ebfS + (size_t)row * 32 + fl * 2) = o;
            }
        }
    } else if (b < CONVU_B + FLAG_B) {
        int k = (b - CONVU_B) * 256 + t;
        if (k < 3 * B) {
            int row;
            if (k < B)          row = users[k];
            else if (k < 2 * B) row = N_USERS + pos[k - B];
            else                row = N_USERS + neg[k - 2 * B];
            flags[row] = 1;
        }
    } else {
        __shared__ int ebuf[256 * SCAT_K];            // 32 KB payloads
        __shared__ unsigned char bbuf[256 * SCAT_K];  // 8 KB bucket ids
        __shared__ int cnt[NBUCK];
        __shared__ int basep[NBUCK];
        int chunk = (b - CONVU_B - FLAG_B) * (256 * SCAT_K);
        if (t < NBUCK) cnt[t] = 0;
        __syncthreads();
        #pragma unroll 8
        for (int k = 0; k < SCAT_K; ++k) {
            int e = chunk + k * 256 + t;
            int idx = k * 256 + t;
            if (e < E) {
                int i = cols[e] - N_USERS;
                cols16[e] = (unsigned short)i;
                int bu = i >> 8;
                ebuf[idx] = ((i & 255) << 17) | rows[e];
                bbuf[idx] = (unsigned char)bu;
                atomicAdd(&cnt[bu], 1);
            } else bbuf[idx] = 255;                    // invalid (>195)
        }
        __syncthreads();
        if (t < NBUCK) {
            int c = cnt[t];
            basep[t] = c ? atomicAdd(&ccur[t], c) : 0;
            cnt[t] = 0;
        }
        __syncthreads();
        #pragma unroll 4
        for (int k = 0; k < SCAT_K; ++k) {
            int idx = k * 256 + t;
            int bu = bbuf[idx];
            if (bu < NBUCK) {
                int pos2 = basep[bu] + atomicAdd(&cnt[bu], 1);
                if (pos2 < BCAP)
                    tmp[(size_t)bu * BCAP + pos2] = ebuf[idx];
            }
        }
    }
}

// ---------------- preprocessing kernel B (R7-proven + degree hist) ----------------
__global__ __launch_bounds__(256) void preB_kernel(
        const int* __restrict__ tmp, const int* __restrict__ ccur,
        const float* __restrict__ embeds,
        int* __restrict__ item_beg, int* __restrict__ item_end,
        int* __restrict__ nbr, unsigned* __restrict__ ebfS,
        unsigned* __restrict__ bb1, float* __restrict__ invrow,
        int* __restrict__ gbins) {
    int b = blockIdx.x, t = threadIdx.x;
    if (b == NBUCK) {
        if (t < 16) {
            *(uint2*)(ebfS + (size_t)N_TOT * 32 + t * 2) = make_uint2(0u, 0u);
            *(uint2*)(bb1  + (size_t)N_TOT * 32 + t * 2) = make_uint2(0u, 0u);
        }
        if (t == 0) invrow[N_TOT] = 0.f;
        return;
    }
    __shared__ int stage[BCAP];    // 48 KB
    __shared__ int hist[256];
    __shared__ int scn[256];
    __shared__ int curs[256];
    __shared__ float inv_s[256];
    int n = ccur[b]; if (n > BCAP) n = BCAP;
    const int* src = tmp + (size_t)b * BCAP;
    hist[t] = 0;
    __syncthreads();
    int n4 = n >> 2;
    const int4* src4 = (const int4*)src;
    for (int p = t; p < n4; p += 256) {
        int4 q = src4[p];
        *(int4*)(stage + p * 4) = q;
        atomicAdd(&hist[q.x >> 17], 1);
        atomicAdd(&hist[q.y >> 17], 1);
        atomicAdd(&hist[q.z >> 17], 1);
        atomicAdd(&hist[q.w >> 17], 1);
    }
    for (int p = (n4 << 2) + t; p < n; p += 256) {
        int q = src[p];
        stage[p] = q;
        atomicAdd(&hist[q >> 17], 1);
    }
    __syncthreads();
    scn[t] = hist[t];
    __syncthreads();
    for (int off = 1; off < 256; off <<= 1) {
        int x = (t >= off) ? scn[t - off] : 0;
        __syncthreads();
        scn[t] += x;
        __syncthreads();
    }
    {
        int excl = scn[t] - hist[t];
        curs[t] = excl;
        int gi = (b << 8) + t;
        float inv = (hist[t] > 0) ? (float)(1.0 / sqrt((double)hist[t])) : 0.f;
        inv_s[t] = inv;
        if (gi < N_ITEMS) {
            item_beg[gi] = b * BCAP + excl;
            item_end[gi] = b * BCAP + excl + hist[t];
            invrow[N_USERS + gi] = inv;
            atomicAdd(&gbins[min(hist[t], 255)], 1);  // degree histogram (perm)
        }
    }
    __syncthreads();
    int* dst = nbr + (size_t)b * BCAP;
    for (int p = t; p < n4; p += 256) {
        int4 q = *(const int4*)(stage + p * 4);
        int p0 = atomicAdd(&curs[q.x >> 17], 1); dst[p0] = q.x & 0x1FFFF;
        int p1 = atomicAdd(&curs[q.y >> 17], 1); dst[p1] = q.y & 0x1FFFF;
        int p2 = atomicAdd(&curs[q.z >> 17], 1); dst[p2] = q.z & 0x1FFFF;
        int p3 = atomicAdd(&curs[q.w >> 17], 1); dst[p3] = q.w & 0x1FFFF;
    }
    for (int p = (n4 << 2) + t; p < n; p += 256) {
        int q = stage[p];
        int pos = atomicAdd(&curs[q >> 17], 1);
        dst[pos] = q & 0x1FFFF;
    }
    int fl = t & 15;
    #pragma unroll
    for (int i = 0; i < 16; ++i) {
        int lr = i * 16 + (t >> 4);
        int gi = (b << 8) + lr;
        if (gi < N_ITEMS) {
            int row = N_USERS + gi;
            float inv = inv_s[lr];
            float4 v4 = *(const float4*)(embeds + (size_t)row * D + fl * 4);
            uint2 o;
            o.x = packbf(inv * v4.x, inv * v4.y);
            o.y = packbf(inv * v4.z, inv * v4.w);
            *(uint2*)(ebfS + (size_t)row * 32 + fl * 2) = o;
        }
    }
}

// ---------------- preC: degree-sorted permutation ----------------
// Every block redundantly prefix-scans the 256-bin global degree histogram in
// LDS (no grid sync needed; gbins is final after preB), then places its 256
// rows via global per-bin cursors. Result: perm groups equal-degree rows, so
// agg waves (4 rows each) have zero degree-uniformization waste (~20% of all
// gather issues in the R7 layout).
__global__ __launch_bounds__(256) void preC_kernel(
        const int* __restrict__ user_ptr, const int* __restrict__ item_beg,
        const int* __restrict__ item_end, const int* __restrict__ gbins,
        int* __restrict__ gcur, int* __restrict__ perm) {
    __shared__ int pre[256];
    int t = threadIdx.x;
    int row = blockIdx.x * 256 + t;
    pre[t] = gbins[t];
    __syncthreads();
    for (int off = 1; off < 256; off <<= 1) {
        int x = (t >= off) ? pre[t - off] : 0;
        __syncthreads();
        pre[t] += x;
        __syncthreads();
    }
    if (row < N_TOT) {
        int deg;
        if (row < N_USERS) deg = user_ptr[row + 1] - user_ptr[row];
        else { int i = row - N_USERS; deg = item_end[i] - item_beg[i]; }
        int bin = min(deg, 255);
        int excl = pre[bin] - gbins[bin];
        int pos = excl + atomicAdd(&gcur[bin], 1);
        perm[pos] = row;
    }
}

// ---------------- propagation (layers 1,2): 4 rows/wave, degree-grouped ----------------
__global__ __launch_bounds__(256) void agg_kernel(
        const unsigned* __restrict__ gsrc,   // scaled bf16 rows, 32 uints/row
        float* __restrict__ nxt, unsigned* __restrict__ nxtb,
        const float* __restrict__ invrow,
        const unsigned char* __restrict__ flags,
        const int* __restrict__ user_ptr, const unsigned short* __restrict__ cols16,
        const int* __restrict__ item_beg, const int* __restrict__ item_end,
        const int* __restrict__ nbr, const int* __restrict__ perm) {
    int wave = (int)((blockIdx.x * blockDim.x + threadIdx.x) >> 6);
    int lane = (int)(threadIdx.x & 63);
    if (wave >= (N_TOT >> 2)) return;        // 37500 waves
    int r  = lane >> 4;                      // row slot 0..3
    int q  = lane & 15;
    int g2 = q >> 3;                         // edge subgroup 0..1
    int fl = q & 7;                          // 16B chunk of the 128B row

    int row = perm[(wave << 2) + r];         // degree-grouped row id
    bool is_user = row < N_USERS;            // per-lane (mixed waves possible)
    int s, epos, dummy;
    const unsigned* sb;
    if (is_user) {
        s = user_ptr[row]; epos = user_ptr[row + 1];
        sb = gsrc + (size_t)N_USERS * 32; dummy = N_ITEMS;
    } else {
        int i = row - N_USERS; s = item_beg[i]; epos = item_end[i];
        sb = gsrc; dummy = N_TOT;
    }
    int deg = epos - s;
    int mdeg = deg;                          // wave-max degree (≈deg after grouping)
    mdeg = max(mdeg, __shfl_xor(mdeg, 16));
    mdeg = max(mdeg, __shfl_xor(mdeg, 32));
    int nchunk = (mdeg + 15) >> 4;

    v2f a0 = {0.f, 0.f}, a1 = {0.f, 0.f}, a2 = {0.f, 0.f}, a3 = {0.f, 0.f};

    for (int ch = 0; ch < nchunk; ++ch) {
        int base = s + (ch << 4);
        int cnt = epos - base;
        if (cnt > 16) cnt = 16;
        int col = dummy;                      // zero-row for idle slots
        if (q < cnt)                          // cnt<=0 -> all dummy
            col = is_user ? (int)cols16[base + q] : nbr[base + q];
        int cm = mdeg - (ch << 4); if (cm > 16) cm = 16;   // uniform
        int tcm = (cm + 1) >> 1;                           // <= 8
        #pragma unroll 8
        for (int t = 0; t < tcm; ++t) {
            int c = __shfl(col, (r << 4) + 2 * t + g2);
            uint4 qv = *(const uint4*)(sb + (size_t)c * 32 + fl * 4);
            v2f p0 = {__uint_as_float(qv.x << 16), __uint_as_float(qv.x & 0xFFFF0000u)};
            v2f p1 = {__uint_as_float(qv.y << 16), __uint_as_float(qv.y & 0xFFFF0000u)};
            v2f p2 = {__uint_as_float(qv.z << 16), __uint_as_float(qv.z & 0xFFFF0000u)};
            v2f p3 = {__uint_as_float(qv.w << 16), __uint_as_float(qv.w & 0xFFFF0000u)};
            a0 += p0; a1 += p1; a2 += p2; a3 += p3;
        }
    }
    float acc[8] = {a0.x, a0.y, a1.x, a1.y, a2.x, a2.y, a3.x, a3.y};
    #pragma unroll
    for (int j = 0; j < 8; ++j)
        acc[j] += __shfl_xor(acc[j], 8);     // combine the two edge subgroups
    if (q < 8) {                             // 8 lanes per row write out
        float inv = invrow[row];
        float f[8];
        #pragma unroll
        for (int j = 0; j < 8; ++j) f[j] = inv * acc[j];
        uint4 o;
        o.x = packbf(inv * f[0], inv * f[1]); o.y = packbf(inv * f[2], inv * f[3]);
        o.z = packbf(inv * f[4], inv * f[5]); o.w = packbf(inv * f[6], inv * f[7]);
        *(uint4*)(nxtb + (size_t)row * 32 + fl * 4) = o;   // 128B line-aligned
        if (flags[row]) {
            size_t ro = (size_t)row * D + fl * 8;
            *(float4*)(nxt + ro)     = make_float4(f[0], f[1], f[2], f[3]);
            *(float4*)(nxt + ro + 4) = make_float4(f[4], f[5], f[6], f[7]);
        }
    }
}

// ---------------- layer 3 fused with epilogue (R0-proven) ----------------
__global__ __launch_bounds__(256) void agg3_fused_kernel(
        const unsigned* __restrict__ gsrc,
        const float* __restrict__ e0, const float* __restrict__ e1,
        const float* __restrict__ e2, const float* __restrict__ invrow,
        const int* __restrict__ users, const int* __restrict__ pos,
        const int* __restrict__ neg,
        const int* __restrict__ user_ptr, const unsigned short* __restrict__ cols16,
        const int* __restrict__ item_beg, const int* __restrict__ item_end,
        const int* __restrict__ nbr,
        float* __restrict__ out, int B) {
    int slot = (int)((blockIdx.x * blockDim.x + threadIdx.x) >> 6);
    int lane = (int)(threadIdx.x & 63);
    if (slot >= 3 * B) return;
    int g  = lane >> 3;
    int fl = lane & 7;

    int row;
    if (slot < B)          row = users[slot];
    else if (slot < 2 * B) row = N_USERS + pos[slot - B];
    else                   row = N_USERS + neg[slot - 2 * B];

    bool is_user = row < N_USERS;
    int s, epos, dummy;
    const unsigned* sb;
    if (is_user) {
        s = user_ptr[row]; epos = user_ptr[row + 1];
        sb = gsrc + (size_t)N_USERS * 32; dummy = N_ITEMS;
    } else {
        int i = row - N_USERS; s = item_beg[i]; epos = item_end[i];
        sb = gsrc; dummy = N_TOT;
    }

    v2f a0 = {0.f, 0.f}, a1 = {0.f, 0.f}, a2 = {0.f, 0.f}, a3 = {0.f, 0.f};

    for (int base = s; base < epos; base += 64) {
        int cnt = epos - base; if (cnt > 64) cnt = 64;
        int col = dummy;
        if (lane < cnt)
            col = is_user ? (int)cols16[base + lane] : nbr[base + lane];
        int tcount = (cnt + 7) >> 3;
        #pragma unroll 8
        for (int t = 0; t < tcount; ++t) {
            int c = __shfl(col, 8 * t + g);
            uint4 q = *(const uint4*)(sb + (size_t)c * 32 + fl * 4);
            v2f p0 = {__uint_as_float(q.x << 16), __uint_as_float(q.x & 0xFFFF0000u)};
            v2f p1 = {__uint_as_float(q.y << 16), __uint_as_float(q.y & 0xFFFF0000u)};
            v2f p2 = {__uint_as_float(q.z << 16), __uint_as_float(q.z & 0xFFFF0000u)};
            v2f p3 = {__uint_as_float(q.w << 16), __uint_as_float(q.w & 0xFFFF0000u)};
            a0 += p0; a1 += p1; a2 += p2; a3 += p3;
        }
    }
    float acc[8] = {a0.x, a0.y, a1.x, a1.y, a2.x, a2.y, a3.x, a3.y};
    #pragma unroll
    for (int j = 0; j < 8; ++j) {
        acc[j] += __shfl_xor(acc[j], 8);
        acc[j] += __shfl_xor(acc[j], 16);
        acc[j] += __shfl_xor(acc[j], 32);
    }
    if (lane < 8) {
        float inv = invrow[row];
        size_t ro = (size_t)row * D + fl * 8;
        float4 x0 = *(const float4*)(e0 + ro), x1 = *(const float4*)(e0 + ro + 4);
        float4 y0 = *(const float4*)(e1 + ro), y1 = *(const float4*)(e1 + ro + 4);
        float4 z0 = *(const float4*)(e2 + ro), z1 = *(const float4*)(e2 + ro + 4);
        float4 r0, r1;
        r0.x = (x0.x + y0.x + z0.x + inv * acc[0]) * 0.25f;
        r0.y = (x0.y + y0.y + z0.y + inv * acc[1]) * 0.25f;
        r0.z = (x0.z + y0.z + z0.z + inv * acc[2]) * 0.25f;
        r0.w = (x0.w + y0.w + z0.w + inv * acc[3]) * 0.25f;
        r1.x = (x1.x + y1.x + z1.x + inv * acc[4]) * 0.25f;
        r1.y = (x1.y + y1.y + z1.y + inv * acc[5]) * 0.25f;
        r1.z = (x1.z + y1.z + z1.z + inv * acc[6]) * 0.25f;
        r1.w = (x1.w + y1.w + z1.w + inv * acc[7]) * 0.25f;
        size_t oo = (size_t)slot * D + fl * 8;
        *(float4*)(out + oo)     = r0;
        *(float4*)(out + oo + 4) = r1;
    }
}

extern "C" void kernel_launch(void* const* d_in, const int* in_sizes, int n_in,
                              void* d_out, int out_size, void* d_ws, size_t ws_size,
                              hipStream_t stream) {
    const float* embeds = (const float*)d_in[0];
    const int*   rows   = (const int*)d_in[2];
    const int*   cols   = (const int*)d_in[3];
    const int*   users  = (const int*)d_in[4];
    const int*   pos    = (const int*)d_in[5];
    const int*   neg    = (const int*)d_in[6];
    const int E2 = in_sizes[1];
    const int E  = E2 / 2;
    const int B  = in_sizes[4];

    char* ws = (char*)d_ws;
    size_t off = 0;
    auto alloc = [&](size_t bytes) { void* p = ws + off; off = (off + bytes + 255) & ~(size_t)255; return p; };
    float*    buf1     = (float*)   alloc((size_t)N_TOT * D * sizeof(float));     // flagged fp32 L1
    float*    buf2     = (float*)   alloc((size_t)N_TOT * D * sizeof(float));     // flagged fp32 L2
    unsigned* ebfS     = (unsigned*)alloc((size_t)(N_TOT + 1) * 32 * sizeof(unsigned)); // scaled bf16 (+zero row); reused as bb2
    unsigned* bb1      = (unsigned*)alloc((size_t)(N_TOT + 1) * 32 * sizeof(unsigned));
    int*      nbr      = (int*)     alloc((size_t)NBUCK * BCAP * sizeof(int));    // padded item CSR (user idx)
    unsigned short* cols16 = (unsigned short*)alloc((size_t)E * sizeof(unsigned short));
    int*      user_ptr = (int*)     alloc((size_t)(N_USERS + 1) * sizeof(int));
    int*      item_beg = (int*)     alloc((size_t)N_ITEMS * sizeof(int));
    int*      item_end = (int*)     alloc((size_t)N_ITEMS * sizeof(int));
    float*    invrow   = (float*)   alloc((size_t)(N_TOT + 1) * sizeof(float));
    int*      perm     = (int*)     alloc((size_t)N_TOT * sizeof(int));
    // ccur + gbins + gcur + flags adjacent -> single memset covers all
    int*      ccur     = (int*)     alloc((size_t)NBUCK * sizeof(int));
    int*      gbins    = (int*)     alloc(256 * sizeof(int));
    int*      gcur     = (int*)     alloc(256 * sizeof(int));
    unsigned char* flags = (unsigned char*)alloc((size_t)N_TOT);
    int*      tmp      = (int*)buf1;   // alias: buf1 written only after preB

    // --- preprocessing (R7-proven + perm build) ---
    size_t zspan = ((char*)flags + N_TOT) - (char*)ccur;
    hipMemsetAsync(ccur, 0, zspan, stream);
    const int scatB = (E + 256 * SCAT_K - 1) / (256 * SCAT_K);
    preA_kernel<<<CONVU_B + FLAG_B + scatB, 256, 0, stream>>>(
        embeds, rows, cols, user_ptr, ebfS, invrow, users, pos, neg, flags,
        ccur, tmp, cols16, gbins, E, B);
    preB_kernel<<<NBUCK + 1, 256, 0, stream>>>(
        tmp, ccur, embeds, item_beg, item_end, nbr, ebfS, bb1, invrow, gbins);
    preC_kernel<<<PERM_B, 256, 0, stream>>>(
        user_ptr, item_beg, item_end, gbins, gcur, perm);

    // --- layers 1,2: 4 rows/wave, degree-grouped ---
    const int blocks = N_TOT / 16;     // 9375
    agg_kernel<<<blocks, 256, 0, stream>>>(ebfS, buf1, bb1, invrow, flags, user_ptr,
                                           cols16, item_beg, item_end, nbr, perm);
    agg_kernel<<<blocks, 256, 0, stream>>>(bb1, buf2, ebfS, invrow, flags, user_ptr,
                                           cols16, item_beg, item_end, nbr, perm);  // bb2 = ebfS

    // --- layer 3 + epilogue fused: only the 3*B output slots ---
    agg3_fused_kernel<<<(3 * B + 3) / 4, 256, 0, stream>>>(
        ebfS, embeds, buf1, buf2, invrow, users, pos, neg,
        user_ptr, cols16, item_beg, item_end, nbr, (float*)d_out, B);
}

// Round 10
// 288.810 us; speedup vs baseline: 3.5100x; 3.5100x over previous
//
#include <hip/hip_runtime.h>
#include <hip/hip_bf16.h>

#define N_USERS 100000
#define N_ITEMS 50000
#define N_TOT   150000
#define D       64
#define NBUCK   ((N_ITEMS + 255) >> 8)   // 196 coarse buckets of 256 items
#define BCAP    12288                    // bucket capacity (mean ~10.2K, +18 sigma)
#define CONVU_B 391                      // ceil(100000/256): user conv+ptr blocks
#define FLAG_B  48                       // ceil(3*4096/256)
#define SCAT_K  32                       // edges per thread in scatter section

typedef float v2f __attribute__((ext_vector_type(2)));

// ---------------- helpers ----------------
__device__ __forceinline__ unsigned bf16rn(float f) {        // fp32 -> bf16 bits (RNE)
    unsigned x = __float_as_uint(f);
    return (x + 0x7FFFu + ((x >> 16) & 1u)) >> 16;
}
__device__ __forceinline__ unsigned packbf(float a, float b) {
    return bf16rn(a) | (bf16rn(b) << 16);
}
__device__ __forceinline__ int lower_bound(const int* __restrict__ a, int n, int key) {
    int lo = 0, hi = n;
    while (lo < hi) {
        int mid = (lo + hi) >> 1;
        if (a[mid] < key) lo = mid + 1; else hi = mid;
    }
    return lo;
}

// ---------------- preprocessing kernel A (R0/R7-proven) ----------------
__global__ __launch_bounds__(256) void preA_kernel(
        const float* __restrict__ embeds, const int* __restrict__ rows,
        const int* __restrict__ cols, int* __restrict__ user_ptr,
        unsigned* __restrict__ ebfS, float* __restrict__ invrow,
        const int* __restrict__ users, const int* __restrict__ pos,
        const int* __restrict__ neg, unsigned char* __restrict__ flags,
        int* __restrict__ ccur, int* __restrict__ tmp,
        unsigned short* __restrict__ cols16, int E, int B) {
    int b = blockIdx.x, t = threadIdx.x;
    if (b < CONVU_B) {
        __shared__ int ptr_s[257];
        __shared__ float inv_s[256];
        int base = b * 256;
        int r = base + t;
        int v = lower_bound(rows, E, r);
        ptr_s[t] = v;
        if (r <= N_USERS) user_ptr[r] = v;
        if (t == 0) ptr_s[256] = lower_bound(rows, E, base + 256);
        __syncthreads();
        if (r < N_USERS) {
            int deg = ptr_s[t + 1] - ptr_s[t];
            float inv = (deg > 0) ? (float)(1.0 / sqrt((double)deg)) : 0.f;
            inv_s[t] = inv;
            invrow[r] = inv;
        } else inv_s[t] = 0.f;
        __syncthreads();
        int fl = t & 15;
        #pragma unroll
        for (int i = 0; i < 16; ++i) {
            int lr = i * 16 + (t >> 4);
            int row = base + lr;
            if (row < N_USERS) {
                float inv = inv_s[lr];
                float4 v4 = *(const float4*)(embeds + (size_t)row * D + fl * 4);
                uint2 o;
                o.x = packbf(inv * v4.x, inv * v4.y);
                o.y = packbf(inv * v4.z, inv * v4.w);
                *(uint2*)(ebfS + (size_t)row * 32 + fl * 2) = o;
            }
        }
    } else if (b < CONVU_B + FLAG_B) {
        int k = (b - CONVU_B) * 256 + t;
        if (k < 3 * B) {
            int row;
            if (k < B)          row = users[k];
            else if (k < 2 * B) row = N_USERS + pos[k - B];
            else                row = N_USERS + neg[k - 2 * B];
            flags[row] = 1;
        }
    } else {
        __shared__ int ebuf[256 * SCAT_K];            // 32 KB payloads
        __shared__ unsigned char bbuf[256 * SCAT_K];  // 8 KB bucket ids
        __shared__ int cnt[NBUCK];
        __shared__ int basep[NBUCK];
        int chunk = (b - CONVU_B - FLAG_B) * (256 * SCAT_K);
        if (t < NBUCK) cnt[t] = 0;
        __syncthreads();
        #pragma unroll 8
        for (int k = 0; k < SCAT_K; ++k) {
            int e = chunk + k * 256 + t;
            int idx = k * 256 + t;
            if (e < E) {
                int i = cols[e] - N_USERS;
                cols16[e] = (unsigned short)i;
                int bu = i >> 8;
                ebuf[idx] = ((i & 255) << 17) | rows[e];
                bbuf[idx] = (unsigned char)bu;
                atomicAdd(&cnt[bu], 1);
            } else bbuf[idx] = 255;                    // invalid (>195)
        }
        __syncthreads();
        if (t < NBUCK) {
            int c = cnt[t];
            basep[t] = c ? atomicAdd(&ccur[t], c) : 0;
            cnt[t] = 0;
        }
        __syncthreads();
        #pragma unroll 4
        for (int k = 0; k < SCAT_K; ++k) {
            int idx = k * 256 + t;
            int bu = bbuf[idx];
            if (bu < NBUCK) {
                int pos2 = basep[bu] + atomicAdd(&cnt[bu], 1);
                if (pos2 < BCAP)
                    tmp[(size_t)bu * BCAP + pos2] = ebuf[idx];
            }
        }
    }
}

// ---------------- preprocessing kernel B (R0/R7-proven) ----------------
__global__ __launch_bounds__(256) void preB_kernel(
        const int* __restrict__ tmp, const int* __restrict__ ccur,
        const float* __restrict__ embeds,
        int* __restrict__ item_beg, int* __restrict__ item_end,
        int* __restrict__ nbr, unsigned* __restrict__ ebfS,
        unsigned* __restrict__ bb1, float* __restrict__ invrow) {
    int b = blockIdx.x, t = threadIdx.x;
    if (b == NBUCK) {
        if (t < 16) {
            *(uint2*)(ebfS + (size_t)N_TOT * 32 + t * 2) = make_uint2(0u, 0u);
            *(uint2*)(bb1  + (size_t)N_TOT * 32 + t * 2) = make_uint2(0u, 0u);
        }
        if (t == 0) invrow[N_TOT] = 0.f;
        return;
    }
    __shared__ int stage[BCAP];    // 48 KB
    __shared__ int hist[256];
    __shared__ int scn[256];
    __shared__ int curs[256];
    __shared__ float inv_s[256];
    int n = ccur[b]; if (n > BCAP) n = BCAP;
    const int* src = tmp + (size_t)b * BCAP;
    hist[t] = 0;
    __syncthreads();
    int n4 = n >> 2;
    const int4* src4 = (const int4*)src;
    for (int p = t; p < n4; p += 256) {
        int4 q = src4[p];
        *(int4*)(stage + p * 4) = q;
        atomicAdd(&hist[q.x >> 17], 1);
        atomicAdd(&hist[q.y >> 17], 1);
        atomicAdd(&hist[q.z >> 17], 1);
        atomicAdd(&hist[q.w >> 17], 1);
    }
    for (int p = (n4 << 2) + t; p < n; p += 256) {
        int q = src[p];
        stage[p] = q;
        atomicAdd(&hist[q >> 17], 1);
    }
    __syncthreads();
    scn[t] = hist[t];
    __syncthreads();
    for (int off = 1; off < 256; off <<= 1) {
        int x = (t >= off) ? scn[t - off] : 0;
        __syncthreads();
        scn[t] += x;
        __syncthreads();
    }
    {
        int excl = scn[t] - hist[t];
        curs[t] = excl;
        int gi = (b << 8) + t;
        float inv = (hist[t] > 0) ? (float)(1.0 / sqrt((double)hist[t])) : 0.f;
        inv_s[t] = inv;
        if (gi < N_ITEMS) {
            item_beg[gi] = b * BCAP + excl;
            item_end[gi] = b * BCAP + excl + hist[t];
            invrow[N_USERS + gi] = inv;
        }
    }
    __syncthreads();
    int* dst = nbr + (size_t)b * BCAP;
    for (int p = t; p < n4; p += 256) {
        int4 q = *(const int4*)(stage + p * 4);
        int p0 = atomicAdd(&curs[q.x >> 17], 1); dst[p0] = q.x & 0x1FFFF;
        int p1 = atomicAdd(&curs[q.y >> 17], 1); dst[p1] = q.y & 0x1FFFF;
        int p2 = atomicAdd(&curs[q.z >> 17], 1); dst[p2] = q.z & 0x1FFFF;
        int p3 = atomicAdd(&curs[q.w >> 17], 1); dst[p3] = q.w & 0x1FFFF;
    }
    for (int p = (n4 << 2) + t; p < n; p += 256) {
        int q = stage[p];
        int pos = atomicAdd(&curs[q >> 17], 1);
        dst[pos] = q & 0x1FFFF;
    }
    int fl = t & 15;
    #pragma unroll
    for (int i = 0; i < 16; ++i) {
        int lr = i * 16 + (t >> 4);
        int gi = (b << 8) + lr;
        if (gi < N_ITEMS) {
            int row = N_USERS + gi;
            float inv = inv_s[lr];
            float4 v4 = *(const float4*)(embeds + (size_t)row * D + fl * 4);
            uint2 o;
            o.x = packbf(inv * v4.x, inv * v4.y);
            o.y = packbf(inv * v4.z, inv * v4.w);
            *(uint2*)(ebfS + (size_t)row * 32 + fl * 2) = o;
        }
    }
}

// ---------------- propagation (layers 1,2): 4 rows/wave + pipelined col loads ----------------
// R7-proven layout (lane = (r<<4)|(g2<<3)|fl, natural row order). New: the
// cols16/nbr index load for chunk ch+1 is issued BEFORE the 8 gathers of chunk
// ch are consumed (depth-1 software pipeline) -> hides the ~200-500cy dependent
// index-load bubble that previously serialized each 16-edge chunk.
__global__ __launch_bounds__(256) void agg_kernel(
        const unsigned* __restrict__ gsrc,   // scaled bf16 rows, 32 uints/row
        float* __restrict__ nxt, unsigned* __restrict__ nxtb,
        const float* __restrict__ invrow,
        const unsigned char* __restrict__ flags,
        const int* __restrict__ user_ptr, const unsigned short* __restrict__ cols16,
        const int* __restrict__ item_beg, const int* __restrict__ item_end,
        const int* __restrict__ nbr) {
    int wave = (int)((blockIdx.x * blockDim.x + threadIdx.x) >> 6);
    int lane = (int)(threadIdx.x & 63);
    if (wave >= (N_TOT >> 2)) return;        // 37500 waves
    int r  = lane >> 4;                      // row slot 0..3
    int q  = lane & 15;
    int g2 = q >> 3;                         // edge subgroup 0..1
    int fl = q & 7;                          // 16B chunk of the 128B row

    int row = (wave << 2) + r;
    bool is_user = row < N_USERS;            // wave-uniform (100000 % 4 == 0)
    int s, epos, dummy;
    const unsigned* sb;
    if (is_user) {
        s = user_ptr[row]; epos = user_ptr[row + 1];
        sb = gsrc + (size_t)N_USERS * 32; dummy = N_ITEMS;
    } else {
        int i = row - N_USERS; s = item_beg[i]; epos = item_end[i];
        sb = gsrc; dummy = N_TOT;
    }
    int deg = epos - s;
    int mdeg = deg;                          // wave-max degree (uniform trip counts)
    mdeg = max(mdeg, __shfl_xor(mdeg, 16));
    mdeg = max(mdeg, __shfl_xor(mdeg, 32));
    int nchunk = (mdeg + 15) >> 4;

    v2f a0 = {0.f, 0.f}, a1 = {0.f, 0.f}, a2 = {0.f, 0.f}, a3 = {0.f, 0.f};

    // prologue: load chunk 0's col indices
    int col = dummy;
    {
        int cnt0 = epos - s;
        if (q < min(cnt0, 16) && nchunk > 0)
            col = is_user ? (int)cols16[s + q] : nbr[s + q];
    }
    for (int ch = 0; ch < nchunk; ++ch) {
        // prefetch chunk ch+1's col indices (independent of this chunk's gathers)
        int ncol = dummy;
        if (ch + 1 < nchunk) {
            int nbase = s + ((ch + 1) << 4);
            int ncnt = epos - nbase;
            if (q < min(ncnt, 16))
                ncol = is_user ? (int)cols16[nbase + q] : nbr[nbase + q];
        }
        int cm = mdeg - (ch << 4); if (cm > 16) cm = 16;   // uniform
        int tcm = (cm + 1) >> 1;                           // <= 8
        #pragma unroll 8
        for (int t = 0; t < tcm; ++t) {
            int c = __shfl(col, (r << 4) + 2 * t + g2);
            uint4 qv = *(const uint4*)(sb + (size_t)c * 32 + fl * 4);
            v2f p0 = {__uint_as_float(qv.x << 16), __uint_as_float(qv.x & 0xFFFF0000u)};
            v2f p1 = {__uint_as_float(qv.y << 16), __uint_as_float(qv.y & 0xFFFF0000u)};
            v2f p2 = {__uint_as_float(qv.z << 16), __uint_as_float(qv.z & 0xFFFF0000u)};
            v2f p3 = {__uint_as_float(qv.w << 16), __uint_as_float(qv.w & 0xFFFF0000u)};
            a0 += p0; a1 += p1; a2 += p2; a3 += p3;
        }
        col = ncol;
    }
    float acc[8] = {a0.x, a0.y, a1.x, a1.y, a2.x, a2.y, a3.x, a3.y};
    #pragma unroll
    for (int j = 0; j < 8; ++j)
        acc[j] += __shfl_xor(acc[j], 8);     // combine the two edge subgroups
    if (q < 8) {                             // 8 lanes per row write out
        float inv = invrow[row];
        float f[8];
        #pragma unroll
        for (int j = 0; j < 8; ++j) f[j] = inv * acc[j];
        uint4 o;
        o.x = packbf(inv * f[0], inv * f[1]); o.y = packbf(inv * f[2], inv * f[3]);
        o.z = packbf(inv * f[4], inv * f[5]); o.w = packbf(inv * f[6], inv * f[7]);
        *(uint4*)(nxtb + (size_t)row * 32 + fl * 4) = o;
        if (flags[row]) {
            size_t ro = (size_t)row * D + fl * 8;
            *(float4*)(nxt + ro)     = make_float4(f[0], f[1], f[2], f[3]);
            *(float4*)(nxt + ro + 4) = make_float4(f[4], f[5], f[6], f[7]);
        }
    }
}

// ---------------- layer 3 fused with epilogue (R0-proven) ----------------
__global__ __launch_bounds__(256) void agg3_fused_kernel(
        const unsigned* __restrict__ gsrc,
        const float* __restrict__ e0, const float* __restrict__ e1,
        const float* __restrict__ e2, const float* __restrict__ invrow,
        const int* __restrict__ users, const int* __restrict__ pos,
        const int* __restrict__ neg,
        const int* __restrict__ user_ptr, const unsigned short* __restrict__ cols16,
        const int* __restrict__ item_beg, const int* __restrict__ item_end,
        const int* __restrict__ nbr,
        float* __restrict__ out, int B) {
    int slot = (int)((blockIdx.x * blockDim.x + threadIdx.x) >> 6);
    int lane = (int)(threadIdx.x & 63);
    if (slot >= 3 * B) return;
    int g  = lane >> 3;
    int fl = lane & 7;

    int row;
    if (slot < B)          row = users[slot];
    else if (slot < 2 * B) row = N_USERS + pos[slot - B];
    else                   row = N_USERS + neg[slot - 2 * B];

    bool is_user = row < N_USERS;
    int s, epos, dummy;
    const unsigned* sb;
    if (is_user) {
        s = user_ptr[row]; epos = user_ptr[row + 1];
        sb = gsrc + (size_t)N_USERS * 32; dummy = N_ITEMS;
    } else {
        int i = row - N_USERS; s = item_beg[i]; epos = item_end[i];
        sb = gsrc; dummy = N_TOT;
    }

    v2f a0 = {0.f, 0.f}, a1 = {0.f, 0.f}, a2 = {0.f, 0.f}, a3 = {0.f, 0.f};

    for (int base = s; base < epos; base += 64) {
        int cnt = epos - base; if (cnt > 64) cnt = 64;
        int col = dummy;
        if (lane < cnt)
            col = is_user ? (int)cols16[base + lane] : nbr[base + lane];
        int tcount = (cnt + 7) >> 3;
        #pragma unroll 8
        for (int t = 0; t < tcount; ++t) {
            int c = __shfl(col, 8 * t + g);
            uint4 q = *(const uint4*)(sb + (size_t)c * 32 + fl * 4);
            v2f p0 = {__uint_as_float(q.x << 16), __uint_as_float(q.x & 0xFFFF0000u)};
            v2f p1 = {__uint_as_float(q.y << 16), __uint_as_float(q.y & 0xFFFF0000u)};
            v2f p2 = {__uint_as_float(q.z << 16), __uint_as_float(q.z & 0xFFFF0000u)};
            v2f p3 = {__uint_as_float(q.w << 16), __uint_as_float(q.w & 0xFFFF0000u)};
            a0 += p0; a1 += p1; a2 += p2; a3 += p3;
        }
    }
    float acc[8] = {a0.x, a0.y, a1.x, a1.y, a2.x, a2.y, a3.x, a3.y};
    #pragma unroll
    for (int j = 0; j < 8; ++j) {
        acc[j] += __shfl_xor(acc[j], 8);
        acc[j] += __shfl_xor(acc[j], 16);
        acc[j] += __shfl_xor(acc[j], 32);
    }
    if (lane < 8) {
        float inv = invrow[row];
        size_t ro = (size_t)row * D + fl * 8;
        float4 x0 = *(const float4*)(e0 + ro), x1 = *(const float4*)(e0 + ro + 4);
        float4 y0 = *(const float4*)(e1 + ro), y1 = *(const float4*)(e1 + ro + 4);
        float4 z0 = *(const float4*)(e2 + ro), z1 = *(const float4*)(e2 + ro + 4);
        float4 r0, r1;
        r0.x = (x0.x + y0.x + z0.x + inv * acc[0]) * 0.25f;
        r0.y = (x0.y + y0.y + z0.y + inv * acc[1]) * 0.25f;
        r0.z = (x0.z + y0.z + z0.z + inv * acc[2]) * 0.25f;
        r0.w = (x0.w + y0.w + z0.w + inv * acc[3]) * 0.25f;
        r1.x = (x1.x + y1.x + z1.x + inv * acc[4]) * 0.25f;
        r1.y = (x1.y + y1.y + z1.y + inv * acc[5]) * 0.25f;
        r1.z = (x1.z + y1.z + z1.z + inv * acc[6]) * 0.25f;
        r1.w = (x1.w + y1.w + z1.w + inv * acc[7]) * 0.25f;
        size_t oo = (size_t)slot * D + fl * 8;
        *(float4*)(out + oo)     = r0;
        *(float4*)(out + oo + 4) = r1;
    }
}

extern "C" void kernel_launch(void* const* d_in, const int* in_sizes, int n_in,
                              void* d_out, int out_size, void* d_ws, size_t ws_size,
                              hipStream_t stream) {
    const float* embeds = (const float*)d_in[0];
    const int*   rows   = (const int*)d_in[2];
    const int*   cols   = (const int*)d_in[3];
    const int*   users  = (const int*)d_in[4];
    const int*   pos    = (const int*)d_in[5];
    const int*   neg    = (const int*)d_in[6];
    const int E2 = in_sizes[1];
    const int E  = E2 / 2;
    const int B  = in_sizes[4];

    char* ws = (char*)d_ws;
    size_t off = 0;
    auto alloc = [&](size_t bytes) { void* p = ws + off; off = (off + bytes + 255) & ~(size_t)255; return p; };
    float*    buf1     = (float*)   alloc((size_t)N_TOT * D * sizeof(float));     // flagged fp32 L1
    float*    buf2     = (float*)   alloc((size_t)N_TOT * D * sizeof(float));     // flagged fp32 L2
    unsigned* ebfS     = (unsigned*)alloc((size_t)(N_TOT + 1) * 32 * sizeof(unsigned)); // scaled bf16 (+zero row); reused as bb2
    unsigned* bb1      = (unsigned*)alloc((size_t)(N_TOT + 1) * 32 * sizeof(unsigned));
    int*      nbr      = (int*)     alloc((size_t)NBUCK * BCAP * sizeof(int));    // padded item CSR (user idx)
    unsigned short* cols16 = (unsigned short*)alloc((size_t)E * sizeof(unsigned short));
    int*      user_ptr = (int*)     alloc((size_t)(N_USERS + 1) * sizeof(int));
    int*      item_beg = (int*)     alloc((size_t)N_ITEMS * sizeof(int));
    int*      item_end = (int*)     alloc((size_t)N_ITEMS * sizeof(int));
    float*    invrow   = (float*)   alloc((size_t)(N_TOT + 1) * sizeof(float));
    // ccur + flags adjacent -> single memset covers both
    int*      ccur     = (int*)     alloc((size_t)NBUCK * sizeof(int));
    unsigned char* flags = (unsigned char*)alloc((size_t)N_TOT);
    int*      tmp      = (int*)buf1;   // alias: buf1 written only after preB

    // --- preprocessing (R7-proven) ---
    size_t zspan = ((char*)flags + N_TOT) - (char*)ccur;
    hipMemsetAsync(ccur, 0, zspan, stream);
    const int scatB = (E + 256 * SCAT_K - 1) / (256 * SCAT_K);
    preA_kernel<<<CONVU_B + FLAG_B + scatB, 256, 0, stream>>>(
        embeds, rows, cols, user_ptr, ebfS, invrow, users, pos, neg, flags,
        ccur, tmp, cols16, E, B);
    preB_kernel<<<NBUCK + 1, 256, 0, stream>>>(
        tmp, ccur, embeds, item_beg, item_end, nbr, ebfS, bb1, invrow);

    // --- layers 1,2: 4 rows/wave, pipelined col loads ---
    const int blocks = N_TOT / 16;     // 9375
    agg_kernel<<<blocks, 256, 0, stream>>>(ebfS, buf1, bb1, invrow, flags, user_ptr,
                                           cols16, item_beg, item_end, nbr);
    agg_kernel<<<blocks, 256, 0, stream>>>(bb1, buf2, ebfS, invrow, flags, user_ptr,
                                           cols16, item_beg, item_end, nbr);  // bb2 = ebfS

    // --- layer 3 + epilogue fused: only the 3*B output slots ---
    agg3_fused_kernel<<<(3 * B + 3) / 4, 256, 0, stream>>>(
        ebfS, embeds, buf1, buf2, invrow, users, pos, neg,
        user_ptr, cols16, item_beg, item_end, nbr, (float*)d_out, B);
}

// Round 11
// 277.691 us; speedup vs baseline: 3.6506x; 1.0400x over previous
//
#include <hip/hip_runtime.h>
#include <hip/hip_bf16.h>

#define N_USERS 100000
#define N_ITEMS 50000
#define N_TOT   150000
#define D       64
#define NBUCK   ((N_ITEMS + 255) >> 8)   // 196 coarse buckets of 256 items
#define BCAP    12288                    // bucket capacity (mean ~10.2K, +18 sigma)
#define CONVU_B 391                      // ceil(100000/256): user conv+ptr blocks
#define FLAG_B  48                       // ceil(3*4096/256)
#define SCAT_K  32                       // edges per thread in scatter section

typedef float v2f __attribute__((ext_vector_type(2)));

// ---------------- helpers ----------------
__device__ __forceinline__ unsigned bf16rn(float f) {        // fp32 -> bf16 bits (RNE)
    unsigned x = __float_as_uint(f);
    return (x + 0x7FFFu + ((x >> 16) & 1u)) >> 16;
}
__device__ __forceinline__ unsigned packbf(float a, float b) {
    return bf16rn(a) | (bf16rn(b) << 16);
}
__device__ __forceinline__ int lower_bound(const int* __restrict__ a, int n, int key) {
    int lo = 0, hi = n;
    while (lo < hi) {
        int mid = (lo + hi) >> 1;
        if (a[mid] < key) lo = mid + 1; else hi = mid;
    }
    return lo;
}

// ---------------- preprocessing kernel A (R0/R7-proven) ----------------
__global__ __launch_bounds__(256) void preA_kernel(
        const float* __restrict__ embeds, const int* __restrict__ rows,
        const int* __restrict__ cols, int* __restrict__ user_ptr,
        unsigned* __restrict__ ebfS, float* __restrict__ invrow,
        const int* __restrict__ users, const int* __restrict__ pos,
        const int* __restrict__ neg, unsigned char* __restrict__ flags,
        int* __restrict__ ccur, int* __restrict__ tmp,
        unsigned short* __restrict__ cols16, int E, int B) {
    int b = blockIdx.x, t = threadIdx.x;
    if (b < CONVU_B) {
        __shared__ int ptr_s[257];
        __shared__ float inv_s[256];
        int base = b * 256;
        int r = base + t;
        int v = lower_bound(rows, E, r);
        ptr_s[t] = v;
        if (r <= N_USERS) user_ptr[r] = v;
        if (t == 0) ptr_s[256] = lower_bound(rows, E, base + 256);
        __syncthreads();
        if (r < N_USERS) {
            int deg = ptr_s[t + 1] - ptr_s[t];
            float inv = (deg > 0) ? (float)(1.0 / sqrt((double)deg)) : 0.f;
            inv_s[t] = inv;
            invrow[r] = inv;
        } else inv_s[t] = 0.f;
        __syncthreads();
        int fl = t & 15;
        #pragma unroll
        for (int i = 0; i < 16; ++i) {
            int lr = i * 16 + (t >> 4);
            int row = base + lr;
            if (row < N_USERS) {
                float inv = inv_s[lr];
                float4 v4 = *(const float4*)(embeds + (size_t)row * D + fl * 4);
                uint2 o;
                o.x = packbf(inv * v4.x, inv * v4.y);
                o.y = packbf(inv * v4.z, inv * v4.w);
                *(uint2*)(ebfS + (size_t)row * 32 + fl * 2) = o;
            }
        }
    } else if (b < CONVU_B + FLAG_B) {
        int k = (b - CONVU_B) * 256 + t;
        if (k < 3 * B) {
            int row;
            if (k < B)          row = users[k];
            else if (k < 2 * B) row = N_USERS + pos[k - B];
            else                row = N_USERS + neg[k - 2 * B];
            flags[row] = 1;
        }
    } else {
        __shared__ int ebuf[256 * SCAT_K];            // 32 KB payloads
        __shared__ unsigned char bbuf[256 * SCAT_K];  // 8 KB bucket ids
        __shared__ int cnt[NBUCK];
        __shared__ int basep[NBUCK];
        int chunk = (b - CONVU_B - FLAG_B) * (256 * SCAT_K);
        if (t < NBUCK) cnt[t] = 0;
        __syncthreads();
        #pragma unroll 8
        for (int k = 0; k < SCAT_K; ++k) {
            int e = chunk + k * 256 + t;
            int idx = k * 256 + t;
            if (e < E) {
                int i = cols[e] - N_USERS;
                cols16[e] = (unsigned short)i;
                int bu = i >> 8;
                ebuf[idx] = ((i & 255) << 17) | rows[e];
                bbuf[idx] = (unsigned char)bu;
                atomicAdd(&cnt[bu], 1);
            } else bbuf[idx] = 255;                    // invalid (>195)
        }
        __syncthreads();
        if (t < NBUCK) {
            int c = cnt[t];
            basep[t] = c ? atomicAdd(&ccur[t], c) : 0;
            cnt[t] = 0;
        }
        __syncthreads();
        #pragma unroll 4
        for (int k = 0; k < SCAT_K; ++k) {
            int idx = k * 256 + t;
            int bu = bbuf[idx];
            if (bu < NBUCK) {
                int pos2 = basep[bu] + atomicAdd(&cnt[bu], 1);
                if (pos2 < BCAP)
                    tmp[(size_t)bu * BCAP + pos2] = ebuf[idx];
            }
        }
    }
}

// ---------------- preprocessing kernel B (R0/R7-proven) ----------------
__global__ __launch_bounds__(256) void preB_kernel(
        const int* __restrict__ tmp, const int* __restrict__ ccur,
        const float* __restrict__ embeds,
        int* __restrict__ item_beg, int* __restrict__ item_end,
        int* __restrict__ nbr, unsigned* __restrict__ ebfS,
        unsigned* __restrict__ bb1, float* __restrict__ invrow) {
    int b = blockIdx.x, t = threadIdx.x;
    if (b == NBUCK) {
        if (t < 16) {
            *(uint2*)(ebfS + (size_t)N_TOT * 32 + t * 2) = make_uint2(0u, 0u);
            *(uint2*)(bb1  + (size_t)N_TOT * 32 + t * 2) = make_uint2(0u, 0u);
        }
        if (t == 0) invrow[N_TOT] = 0.f;
        return;
    }
    __shared__ int stage[BCAP];    // 48 KB
    __shared__ int hist[256];
    __shared__ int scn[256];
    __shared__ int curs[256];
    __shared__ float inv_s[256];
    int n = ccur[b]; if (n > BCAP) n = BCAP;
    const int* src = tmp + (size_t)b * BCAP;
    hist[t] = 0;
    __syncthreads();
    int n4 = n >> 2;
    const int4* src4 = (const int4*)src;
    for (int p = t; p < n4; p += 256) {
        int4 q = src4[p];
        *(int4*)(stage + p * 4) = q;
        atomicAdd(&hist[q.x >> 17], 1);
        atomicAdd(&hist[q.y >> 17], 1);
        atomicAdd(&hist[q.z >> 17], 1);
        atomicAdd(&hist[q.w >> 17], 1);
    }
    for (int p = (n4 << 2) + t; p < n; p += 256) {
        int q = src[p];
        stage[p] = q;
        atomicAdd(&hist[q >> 17], 1);
    }
    __syncthreads();
    scn[t] = hist[t];
    __syncthreads();
    for (int off = 1; off < 256; off <<= 1) {
        int x = (t >= off) ? scn[t - off] : 0;
        __syncthreads();
        scn[t] += x;
        __syncthreads();
    }
    {
        int excl = scn[t] - hist[t];
        curs[t] = excl;
        int gi = (b << 8) + t;
        float inv = (hist[t] > 0) ? (float)(1.0 / sqrt((double)hist[t])) : 0.f;
        inv_s[t] = inv;
        if (gi < N_ITEMS) {
            item_beg[gi] = b * BCAP + excl;
            item_end[gi] = b * BCAP + excl + hist[t];
            invrow[N_USERS + gi] = inv;
        }
    }
    __syncthreads();
    int* dst = nbr + (size_t)b * BCAP;
    for (int p = t; p < n4; p += 256) {
        int4 q = *(const int4*)(stage + p * 4);
        int p0 = atomicAdd(&curs[q.x >> 17], 1); dst[p0] = q.x & 0x1FFFF;
        int p1 = atomicAdd(&curs[q.y >> 17], 1); dst[p1] = q.y & 0x1FFFF;
        int p2 = atomicAdd(&curs[q.z >> 17], 1); dst[p2] = q.z & 0x1FFFF;
        int p3 = atomicAdd(&curs[q.w >> 17], 1); dst[p3] = q.w & 0x1FFFF;
    }
    for (int p = (n4 << 2) + t; p < n; p += 256) {
        int q = stage[p];
        int pos = atomicAdd(&curs[q >> 17], 1);
        dst[pos] = q & 0x1FFFF;
    }
    int fl = t & 15;
    #pragma unroll
    for (int i = 0; i < 16; ++i) {
        int lr = i * 16 + (t >> 4);
        int gi = (b << 8) + lr;
        if (gi < N_ITEMS) {
            int row = N_USERS + gi;
            float inv = inv_s[lr];
            float4 v4 = *(const float4*)(embeds + (size_t)row * D + fl * 4);
            uint2 o;
            o.x = packbf(inv * v4.x, inv * v4.y);
            o.y = packbf(inv * v4.z, inv * v4.w);
            *(uint2*)(ebfS + (size_t)row * 32 + fl * 2) = o;
        }
    }
}

// ---------------- propagation (layers 1,2): 4 rows/wave, batched gathers ----------------
// R10 base + MLP fix: VGPR_Count=20 proved the compiler serialized the 8
// gathers (32 VGPRs of payload cannot fit in 20). Split each chunk into
// (a) 8 fully-unrolled statically-indexed uint4 loads -> all issued before
// any wait, (b) 8 unpack+accumulate steps. Dummy slots load the zero row
// (L1-broadcast, ~free) so the loop is branchless and fully static.
__global__ __launch_bounds__(256) void agg_kernel(
        const unsigned* __restrict__ gsrc,   // scaled bf16 rows, 32 uints/row
        float* __restrict__ nxt, unsigned* __restrict__ nxtb,
        const float* __restrict__ invrow,
        const unsigned char* __restrict__ flags,
        const int* __restrict__ user_ptr, const unsigned short* __restrict__ cols16,
        const int* __restrict__ item_beg, const int* __restrict__ item_end,
        const int* __restrict__ nbr) {
    int wave = (int)((blockIdx.x * blockDim.x + threadIdx.x) >> 6);
    int lane = (int)(threadIdx.x & 63);
    if (wave >= (N_TOT >> 2)) return;        // 37500 waves
    int r  = lane >> 4;                      // row slot 0..3
    int q  = lane & 15;
    int g2 = q >> 3;                         // edge subgroup 0..1
    int fl = q & 7;                          // 16B chunk of the 128B row

    int row = (wave << 2) + r;
    bool is_user = row < N_USERS;            // wave-uniform (100000 % 4 == 0)
    int s, epos, dummy;
    const unsigned* sb;
    if (is_user) {
        s = user_ptr[row]; epos = user_ptr[row + 1];
        sb = gsrc + (size_t)N_USERS * 32; dummy = N_ITEMS;
    } else {
        int i = row - N_USERS; s = item_beg[i]; epos = item_end[i];
        sb = gsrc; dummy = N_TOT;
    }
    int deg = epos - s;
    int mdeg = deg;                          // wave-max degree (uniform trip counts)
    mdeg = max(mdeg, __shfl_xor(mdeg, 16));
    mdeg = max(mdeg, __shfl_xor(mdeg, 32));
    int nchunk = (mdeg + 15) >> 4;

    v2f a0 = {0.f, 0.f}, a1 = {0.f, 0.f}, a2 = {0.f, 0.f}, a3 = {0.f, 0.f};

    // prologue: load chunk 0's col indices
    int col = dummy;
    {
        int cnt0 = epos - s;
        if (q < min(cnt0, 16) && nchunk > 0)
            col = is_user ? (int)cols16[s + q] : nbr[s + q];
    }
    for (int ch = 0; ch < nchunk; ++ch) {
        // prefetch chunk ch+1's col indices (independent of this chunk's gathers)
        int ncol = dummy;
        if (ch + 1 < nchunk) {
            int nbase = s + ((ch + 1) << 4);
            int ncnt = epos - nbase;
            if (q < min(ncnt, 16))
                ncol = is_user ? (int)cols16[nbase + q] : nbr[nbase + q];
        }
        // phase a: issue all 8 gathers (static unroll -> 8 outstanding loads)
        uint4 qv[8];
        #pragma unroll
        for (int t = 0; t < 8; ++t) {
            int c = __shfl(col, (r << 4) + 2 * t + g2);
            qv[t] = *(const uint4*)(sb + (size_t)c * 32 + fl * 4);
        }
        // phase b: unpack + accumulate
        #pragma unroll
        for (int t = 0; t < 8; ++t) {
            v2f p0 = {__uint_as_float(qv[t].x << 16), __uint_as_float(qv[t].x & 0xFFFF0000u)};
            v2f p1 = {__uint_as_float(qv[t].y << 16), __uint_as_float(qv[t].y & 0xFFFF0000u)};
            v2f p2 = {__uint_as_float(qv[t].z << 16), __uint_as_float(qv[t].z & 0xFFFF0000u)};
            v2f p3 = {__uint_as_float(qv[t].w << 16), __uint_as_float(qv[t].w & 0xFFFF0000u)};
            a0 += p0; a1 += p1; a2 += p2; a3 += p3;
        }
        col = ncol;
    }
    float acc[8] = {a0.x, a0.y, a1.x, a1.y, a2.x, a2.y, a3.x, a3.y};
    #pragma unroll
    for (int j = 0; j < 8; ++j)
        acc[j] += __shfl_xor(acc[j], 8);     // combine the two edge subgroups
    if (q < 8) {                             // 8 lanes per row write out
        float inv = invrow[row];
        float f[8];
        #pragma unroll
        for (int j = 0; j < 8; ++j) f[j] = inv * acc[j];
        uint4 o;
        o.x = packbf(inv * f[0], inv * f[1]); o.y = packbf(inv * f[2], inv * f[3]);
        o.z = packbf(inv * f[4], inv * f[5]); o.w = packbf(inv * f[6], inv * f[7]);
        *(uint4*)(nxtb + (size_t)row * 32 + fl * 4) = o;
        if (flags[row]) {
            size_t ro = (size_t)row * D + fl * 8;
            *(float4*)(nxt + ro)     = make_float4(f[0], f[1], f[2], f[3]);
            *(float4*)(nxt + ro + 4) = make_float4(f[4], f[5], f[6], f[7]);
        }
    }
}

// ---------------- layer 3 fused with epilogue (R0-proven) ----------------
__global__ __launch_bounds__(256) void agg3_fused_kernel(
        const unsigned* __restrict__ gsrc,
        const float* __restrict__ e0, const float* __restrict__ e1,
        const float* __restrict__ e2, const float* __restrict__ invrow,
        const int* __restrict__ users, const int* __restrict__ pos,
        const int* __restrict__ neg,
        const int* __restrict__ user_ptr, const unsigned short* __restrict__ cols16,
        const int* __restrict__ item_beg, const int* __restrict__ item_end,
        const int* __restrict__ nbr,
        float* __restrict__ out, int B) {
    int slot = (int)((blockIdx.x * blockDim.x + threadIdx.x) >> 6);
    int lane = (int)(threadIdx.x & 63);
    if (slot >= 3 * B) return;
    int g  = lane >> 3;
    int fl = lane & 7;

    int row;
    if (slot < B)          row = users[slot];
    else if (slot < 2 * B) row = N_USERS + pos[slot - B];
    else                   row = N_USERS + neg[slot - 2 * B];

    bool is_user = row < N_USERS;
    int s, epos, dummy;
    const unsigned* sb;
    if (is_user) {
        s = user_ptr[row]; epos = user_ptr[row + 1];
        sb = gsrc + (size_t)N_USERS * 32; dummy = N_ITEMS;
    } else {
        int i = row - N_USERS; s = item_beg[i]; epos = item_end[i];
        sb = gsrc; dummy = N_TOT;
    }

    v2f a0 = {0.f, 0.f}, a1 = {0.f, 0.f}, a2 = {0.f, 0.f}, a3 = {0.f, 0.f};

    for (int base = s; base < epos; base += 64) {
        int cnt = epos - base; if (cnt > 64) cnt = 64;
        int col = dummy;
        if (lane < cnt)
            col = is_user ? (int)cols16[base + lane] : nbr[base + lane];
        int tcount = (cnt + 7) >> 3;
        #pragma unroll 8
        for (int t = 0; t < tcount; ++t) {
            int c = __shfl(col, 8 * t + g);
            uint4 q = *(const uint4*)(sb + (size_t)c * 32 + fl * 4);
            v2f p0 = {__uint_as_float(q.x << 16), __uint_as_float(q.x & 0xFFFF0000u)};
            v2f p1 = {__uint_as_float(q.y << 16), __uint_as_float(q.y & 0xFFFF0000u)};
            v2f p2 = {__uint_as_float(q.z << 16), __uint_as_float(q.z & 0xFFFF0000u)};
            v2f p3 = {__uint_as_float(q.w << 16), __uint_as_float(q.w & 0xFFFF0000u)};
            a0 += p0; a1 += p1; a2 += p2; a3 += p3;
        }
    }
    float acc[8] = {a0.x, a0.y, a1.x, a1.y, a2.x, a2.y, a3.x, a3.y};
    #pragma unroll
    for (int j = 0; j < 8; ++j) {
        acc[j] += __shfl_xor(acc[j], 8);
        acc[j] += __shfl_xor(acc[j], 16);
        acc[j] += __shfl_xor(acc[j], 32);
    }
    if (lane < 8) {
        float inv = invrow[row];
        size_t ro = (size_t)row * D + fl * 8;
        float4 x0 = *(const float4*)(e0 + ro), x1 = *(const float4*)(e0 + ro + 4);
        float4 y0 = *(const float4*)(e1 + ro), y1 = *(const float4*)(e1 + ro + 4);
        float4 z0 = *(const float4*)(e2 + ro), z1 = *(const float4*)(e2 + ro + 4);
        float4 r0, r1;
        r0.x = (x0.x + y0.x + z0.x + inv * acc[0]) * 0.25f;
        r0.y = (x0.y + y0.y + z0.y + inv * acc[1]) * 0.25f;
        r0.z = (x0.z + y0.z + z0.z + inv * acc[2]) * 0.25f;
        r0.w = (x0.w + y0.w + z0.w + inv * acc[3]) * 0.25f;
        r1.x = (x1.x + y1.x + z1.x + inv * acc[4]) * 0.25f;
        r1.y = (x1.y + y1.y + z1.y + inv * acc[5]) * 0.25f;
        r1.z = (x1.z + y1.z + z1.z + inv * acc[6]) * 0.25f;
        r1.w = (x1.w + y1.w + z1.w + inv * acc[7]) * 0.25f;
        size_t oo = (size_t)slot * D + fl * 8;
        *(float4*)(out + oo)     = r0;
        *(float4*)(out + oo + 4) = r1;
    }
}

extern "C" void kernel_launch(void* const* d_in, const int* in_sizes, int n_in,
                              void* d_out, int out_size, void* d_ws, size_t ws_size,
                              hipStream_t stream) {
    const float* embeds = (const float*)d_in[0];
    const int*   rows   = (const int*)d_in[2];
    const int*   cols   = (const int*)d_in[3];
    const int*   users  = (const int*)d_in[4];
    const int*   pos    = (const int*)d_in[5];
    const int*   neg    = (const int*)d_in[6];
    const int E2 = in_sizes[1];
    const int E  = E2 / 2;
    const int B  = in_sizes[4];

    char* ws = (char*)d_ws;
    size_t off = 0;
    auto alloc = [&](size_t bytes) { void* p = ws + off; off = (off + bytes + 255) & ~(size_t)255; return p; };
    float*    buf1     = (float*)   alloc((size_t)N_TOT * D * sizeof(float));     // flagged fp32 L1
    float*    buf2     = (float*)   alloc((size_t)N_TOT * D * sizeof(float));     // flagged fp32 L2
    unsigned* ebfS     = (unsigned*)alloc((size_t)(N_TOT + 1) * 32 * sizeof(unsigned)); // scaled bf16 (+zero row); reused as bb2
    unsigned* bb1      = (unsigned*)alloc((size_t)(N_TOT + 1) * 32 * sizeof(unsigned));
    int*      nbr      = (int*)     alloc((size_t)NBUCK * BCAP * sizeof(int));    // padded item CSR (user idx)
    unsigned short* cols16 = (unsigned short*)alloc((size_t)E * sizeof(unsigned short));
    int*      user_ptr = (int*)     alloc((size_t)(N_USERS + 1) * sizeof(int));
    int*      item_beg = (int*)     alloc((size_t)N_ITEMS * sizeof(int));
    int*      item_end = (int*)     alloc((size_t)N_ITEMS * sizeof(int));
    float*    invrow   = (float*)   alloc((size_t)(N_TOT + 1) * sizeof(float));
    // ccur + flags adjacent -> single memset covers both
    int*      ccur     = (int*)     alloc((size_t)NBUCK * sizeof(int));
    unsigned char* flags = (unsigned char*)alloc((size_t)N_TOT);
    int*      tmp      = (int*)buf1;   // alias: buf1 written only after preB

    // --- preprocessing (R7-proven) ---
    size_t zspan = ((char*)flags + N_TOT) - (char*)ccur;
    hipMemsetAsync(ccur, 0, zspan, stream);
    const int scatB = (E + 256 * SCAT_K - 1) / (256 * SCAT_K);
    preA_kernel<<<CONVU_B + FLAG_B + scatB, 256, 0, stream>>>(
        embeds, rows, cols, user_ptr, ebfS, invrow, users, pos, neg, flags,
        ccur, tmp, cols16, E, B);
    preB_kernel<<<NBUCK + 1, 256, 0, stream>>>(
        tmp, ccur, embeds, item_beg, item_end, nbr, ebfS, bb1, invrow);

    // --- layers 1,2: 4 rows/wave, batched gathers + pipelined col loads ---
    const int blocks = N_TOT / 16;     // 9375
    agg_kernel<<<blocks, 256, 0, stream>>>(ebfS, buf1, bb1, invrow, flags, user_ptr,
                                           cols16, item_beg, item_end, nbr);
    agg_kernel<<<blocks, 256, 0, stream>>>(bb1, buf2, ebfS, invrow, flags, user_ptr,
                                           cols16, item_beg, item_end, nbr);  // bb2 = ebfS

    // --- layer 3 + epilogue fused: only the 3*B output slots ---
    agg3_fused_kernel<<<(3 * B + 3) / 4, 256, 0, stream>>>(
        ebfS, embeds, buf1, buf2, invrow, users, pos, neg,
        user_ptr, cols16, item_beg, item_end, nbr, (float*)d_out, B);
}